// Round 1
// baseline (2109.764 us; speedup 1.0000x reference)
//
#include <hip/hip_runtime.h>

#define NN 16
#define CIN 256
#define COUT 256
#define LL 300
#define VV 25
#define VP 28      // padded V for 16B-aligned rows (28*4 = 112 B, multiple of 16)
#define PP 3
#define KS 9

// K1: fused 1x1 conv + graph aggregation (+bias) -> h[(n*LL+l)*COUT*VP + c*VP + w]
__global__ __launch_bounds__(256) void k1_conv_agg(
    const float* __restrict__ x,      // (N, CIN, L, V)
    const float* __restrict__ A,      // (P, V, V)
    const float* __restrict__ conv_w, // (COUT*P, CIN)
    const float* __restrict__ conv_b, // (COUT*P)
    const float* __restrict__ ei,     // (P, V*V)
    float* __restrict__ h)
{
    __shared__ float xs[CIN * VP];       // x[n,:,l,:] staged, padded
    __shared__ float AwT[PP * VV * VP];  // [p][w][v] transposed, padded
    __shared__ float cs[PP * VV];        // colsum over v: [p][w]

    const int l = blockIdx.x, n = blockIdx.y, t = threadIdx.x;

    // stage Aw transposed: AwT[p][w][v] = A[p][v][w] * ei[p][v][w]
    for (int idx = t; idx < PP * VV * VV; idx += 256) {
        int p = idx / (VV * VV), r = idx % (VV * VV), v = r / VV, w = r % VV;
        AwT[(p * VV + w) * VP + v] = A[idx] * ei[idx];
    }
    // stage x slab: xs[ci][v] = x[n, ci, l, v]
    for (int idx = t; idx < CIN * VV; idx += 256) {
        int ci = idx / VV, v = idx % VV;
        xs[ci * VP + v] = x[((n * CIN + ci) * LL + l) * VV + v];
    }
    __syncthreads();
    if (t < PP * VV) {
        float s = 0.f;
        #pragma unroll
        for (int v = 0; v < VV; ++v) s += AwT[t * VP + v];
        cs[t] = s;
    }
    __syncthreads();

    // main GEMM: thread t = output channel c; rows c, 256+c, 512+c of conv_w
    const float* rp0 = conv_w + t * CIN;
    const float* rp1 = conv_w + (COUT + t) * CIN;
    const float* rp2 = conv_w + (2 * COUT + t) * CIN;

    float acc0[VV], acc1[VV], acc2[VV];
    #pragma unroll
    for (int v = 0; v < VV; ++v) { acc0[v] = 0.f; acc1[v] = 0.f; acc2[v] = 0.f; }

    for (int ci0 = 0; ci0 < CIN; ci0 += 4) {
        const float4 wa = *(const float4*)(rp0 + ci0);
        const float4 wb = *(const float4*)(rp1 + ci0);
        const float4 wc = *(const float4*)(rp2 + ci0);
        #pragma unroll
        for (int j = 0; j < 4; ++j) {
            const float w0 = (&wa.x)[j], w1 = (&wb.x)[j], w2 = (&wc.x)[j];
            const float* xr = &xs[(ci0 + j) * VP];
            #pragma unroll
            for (int vq = 0; vq < 24; vq += 4) {
                const float4 xv = *(const float4*)(xr + vq);
                acc0[vq + 0] += w0 * xv.x; acc1[vq + 0] += w1 * xv.x; acc2[vq + 0] += w2 * xv.x;
                acc0[vq + 1] += w0 * xv.y; acc1[vq + 1] += w1 * xv.y; acc2[vq + 1] += w2 * xv.y;
                acc0[vq + 2] += w0 * xv.z; acc1[vq + 2] += w1 * xv.z; acc2[vq + 2] += w2 * xv.z;
                acc0[vq + 3] += w0 * xv.w; acc1[vq + 3] += w1 * xv.w; acc2[vq + 3] += w2 * xv.w;
            }
            const float xl = xr[24];
            acc0[24] += w0 * xl; acc1[24] += w1 * xl; acc2[24] += w2 * xl;
        }
    }

    // aggregation over v with Aw, plus bias routed through colsum
    const float b0 = conv_b[t], b1 = conv_b[COUT + t], b2 = conv_b[2 * COUT + t];
    float* hp = h + ((size_t)(n * LL + l) * COUT + t) * VP;
    for (int w = 0; w < VV; ++w) {
        float s = b0 * cs[w] + b1 * cs[VV + w] + b2 * cs[2 * VV + w];
        const float* a0 = &AwT[(0 * VV + w) * VP];
        const float* a1 = &AwT[(1 * VV + w) * VP];
        const float* a2 = &AwT[(2 * VV + w) * VP];
        float s0 = 0.f, s1 = 0.f, s2 = 0.f;
        #pragma unroll
        for (int vq = 0; vq < 24; vq += 4) {
            const float4 f0 = *(const float4*)(a0 + vq);
            const float4 f1 = *(const float4*)(a1 + vq);
            const float4 f2 = *(const float4*)(a2 + vq);
            s0 += acc0[vq + 0] * f0.x + acc0[vq + 1] * f0.y + acc0[vq + 2] * f0.z + acc0[vq + 3] * f0.w;
            s1 += acc1[vq + 0] * f1.x + acc1[vq + 1] * f1.y + acc1[vq + 2] * f1.z + acc1[vq + 3] * f1.w;
            s2 += acc2[vq + 0] * f2.x + acc2[vq + 1] * f2.y + acc2[vq + 2] * f2.z + acc2[vq + 3] * f2.w;
        }
        s += acc0[24] * a0[24] + acc1[24] * a1[24] + acc2[24] * a2[24];
        hp[w] = s + s0 + s1 + s2;
    }
}

// K2: 9-tap causal temporal sum + LayerNorm(C,V) + relu + residual + relu
__global__ __launch_bounds__(256) void k2_temporal_ln(
    const float* __restrict__ h,
    const float* __restrict__ x,
    const float* __restrict__ gamma,  // (COUT,1,V)
    const float* __restrict__ beta,
    float* __restrict__ out)
{
    const int m = blockIdx.x, n = blockIdx.y, t = threadIdx.x;  // t = channel c
    float z[VV];
    #pragma unroll
    for (int w = 0; w < VV; ++w) z[w] = 0.f;

    const int l0 = (m >= KS - 1) ? (m - (KS - 1)) : 0;
    for (int l = l0; l <= m; ++l) {
        const float* hp = h + ((size_t)(n * LL + l) * COUT + t) * VP;
        #pragma unroll
        for (int w = 0; w < 24; w += 4) {
            const float4 f = *(const float4*)(hp + w);
            z[w] += f.x; z[w + 1] += f.y; z[w + 2] += f.z; z[w + 3] += f.w;
        }
        z[24] += hp[24];
    }

    float s1 = 0.f, s2 = 0.f;
    #pragma unroll
    for (int w = 0; w < VV; ++w) { s1 += z[w]; s2 += z[w] * z[w]; }

    __shared__ float rs[4], rq[4], stats[2];
    #pragma unroll
    for (int off = 32; off; off >>= 1) { s1 += __shfl_down(s1, off); s2 += __shfl_down(s2, off); }
    const int wid = t >> 6, lane = t & 63;
    if (lane == 0) { rs[wid] = s1; rq[wid] = s2; }
    __syncthreads();
    if (t == 0) {
        const float S1 = rs[0] + rs[1] + rs[2] + rs[3];
        const float S2 = rq[0] + rq[1] + rq[2] + rq[3];
        const float inv = 1.f / (COUT * VV);
        const float mu = S1 * inv;
        const float var = S2 * inv - mu * mu;
        stats[0] = mu;
        stats[1] = rsqrtf(var + 1e-5f);
    }
    __syncthreads();
    const float mu = stats[0], rsd = stats[1];

    const float* gp = gamma + t * VV;
    const float* bp = beta + t * VV;
    const float* xp = x + ((size_t)(n * CIN + t) * LL + m) * VV;
    float* op = out + ((size_t)(n * COUT + t) * LL + m) * VV;
    #pragma unroll
    for (int w = 0; w < VV; ++w) {
        float val = (z[w] - mu) * rsd * gp[w] + bp[w];
        val = fmaxf(val, 0.f);
        val += xp[w];
        op[w] = fmaxf(val, 0.f);
    }
}

extern "C" void kernel_launch(void* const* d_in, const int* in_sizes, int n_in,
                              void* d_out, int out_size, void* d_ws, size_t ws_size,
                              hipStream_t stream) {
    const float* x      = (const float*)d_in[0];
    const float* A      = (const float*)d_in[1];
    const float* conv_w = (const float*)d_in[2];
    const float* conv_b = (const float*)d_in[3];
    const float* gamma  = (const float*)d_in[4];
    const float* beta   = (const float*)d_in[5];
    const float* ei     = (const float*)d_in[6];
    float* out = (float*)d_out;
    float* h = (float*)d_ws;  // needs 16*300*256*28*4 = 137.6 MB

    dim3 grid(LL, NN);
    k1_conv_agg<<<grid, 256, 0, stream>>>(x, A, conv_w, conv_b, ei, h);
    k2_temporal_ln<<<grid, 256, 0, stream>>>(h, x, gamma, beta, out);
}

// Round 2
// 592.427 us; speedup vs baseline: 3.5612x; 3.5612x over previous
//
#include <hip/hip_runtime.h>

#define NN 16
#define CIN 256
#define COUT 256
#define LL 300
#define VV 25
#define PP 3
#define KS 9
#define KK 768                 // GEMM K = P*CIN
#define MM (NN*LL*VV)          // 120000 GEMM rows
#define MPAD 120064            // 938 * 128
#define MBLK 938

typedef float floatx4 __attribute__((ext_vector_type(4)));
typedef short short8 __attribute__((ext_vector_type(8)));

__device__ __forceinline__ unsigned short f2bf(float f) {
    unsigned u = __builtin_bit_cast(unsigned, f);
    u += 0x7fff + ((u >> 16) & 1);          // round-to-nearest-even
    return (unsigned short)(u >> 16);
}
__device__ __forceinline__ float bf2f(unsigned short h) {
    unsigned u = ((unsigned)h) << 16;
    return __builtin_bit_cast(float, u);
}
__device__ __forceinline__ void gl2lds16(const void* g, void* l) {
    __builtin_amdgcn_global_load_lds(
        (const __attribute__((address_space(1))) void*)g,
        (__attribute__((address_space(3))) void*)l, 16, 0, 0);
}

// ---------------- prep: W2T (bf16, N x K), bias2[c][w], zero xa pad rows ----
__global__ __launch_bounds__(256) void k_prep(
    const float* __restrict__ A, const float* __restrict__ conv_w,
    const float* __restrict__ conv_b, const float* __restrict__ ei,
    unsigned short* __restrict__ w2t, float* __restrict__ bias2,
    unsigned short* __restrict__ xa)
{
    const int t = blockIdx.x * 256 + threadIdx.x;
    const int nthr = gridDim.x * 256;
    // W2T[c][k=(p,ci)] = bf16(conv_w[p*256+c][ci])
    for (int idx = t; idx < COUT * KK; idx += nthr) {
        int c = idx / KK, k = idx % KK, p = k >> 8, ci = k & 255;
        w2t[idx] = f2bf(conv_w[(p * COUT + c) * CIN + ci]);
    }
    // bias2[c][w] = sum_p b[p,c] * sum_v Aw[p,v,w]
    for (int idx = t; idx < COUT * VV; idx += nthr) {
        int c = idx / VV, w = idx % VV;
        float s = 0.f;
        for (int p = 0; p < PP; ++p) {
            float cs = 0.f;
            for (int v = 0; v < VV; ++v) {
                int a = (p * VV + v) * VV + w;
                cs += A[a] * ei[a];
            }
            s += conv_b[p * COUT + c] * cs;
        }
        bias2[idx] = s;
    }
    // zero xa pad rows
    for (int idx = t; idx < (MPAD - MM) * KK; idx += nthr)
        xa[(size_t)MM * KK + idx] = 0;
}

// ---------------- pre-aggregation: xa[(n,l,w)][(p,ci)] = sum_v x*Aw --------
__global__ __launch_bounds__(256) void k_agg(
    const float* __restrict__ x, const float* __restrict__ A,
    const float* __restrict__ ei, unsigned short* __restrict__ xa)
{
    __shared__ float Aw[PP * VV * VV];
    const int l = blockIdx.x, n = blockIdx.y, t = threadIdx.x;  // t = ci
    for (int idx = t; idx < PP * VV * VV; idx += 256)
        Aw[idx] = A[idx] * ei[idx];
    __syncthreads();

    float xv[VV];
    const float* xp = x + ((size_t)(n * CIN + t) * LL + l) * VV;
    #pragma unroll
    for (int v = 0; v < VV; ++v) xv[v] = xp[v];

    const size_t mrow = (size_t)(n * LL + l) * VV;
    #pragma unroll
    for (int p = 0; p < PP; ++p) {
        float acc[VV];
        #pragma unroll
        for (int w = 0; w < VV; ++w) acc[w] = 0.f;
        #pragma unroll
        for (int v = 0; v < VV; ++v) {
            const float xvv = xv[v];
            const float* ar = &Aw[(p * VV + v) * VV];
            #pragma unroll
            for (int w = 0; w < VV; ++w) acc[w] += xvv * ar[w];
        }
        #pragma unroll
        for (int w = 0; w < VV; ++w)
            xa[(mrow + w) * KK + p * CIN + t] = f2bf(acc[w]);
    }
}

// ---------------- GEMM: z[m][c] = xa[m][:] . w2t[c][:]  (bf16 MFMA) --------
__global__ __launch_bounds__(256) void k_gemm(
    const unsigned short* __restrict__ xa,
    const unsigned short* __restrict__ w2t,
    unsigned short* __restrict__ z)
{
    __shared__ __align__(16) unsigned short As[128 * 32];
    __shared__ __align__(16) unsigned short Bs[128 * 32];
    const int t = threadIdx.x, wv = t >> 6, ln = t & 63;
    const int m0 = blockIdx.x * 128, c0 = blockIdx.y * 128;

    floatx4 acc[4][4];
    #pragma unroll
    for (int i = 0; i < 4; ++i)
        #pragma unroll
        for (int j = 0; j < 4; ++j)
            acc[i][j] = (floatx4){0.f, 0.f, 0.f, 0.f};

    const int srow = wv * 32 + (ln >> 2);   // staging row (this lane)
    const int scol = (ln & 3) * 8;          // staging k-offset (elems)
    const int mw = (wv >> 1) * 64, nw = (wv & 1) * 64;
    const int frow = ln & 15, fcol = (ln >> 4) * 8;

    for (int kt = 0; kt < KK / 32; ++kt) {
        const int k0 = kt * 32;
        __syncthreads();
        gl2lds16(xa  + (size_t)(m0 + srow)      * KK + k0 + scol, &As[(wv * 32) * 32]);
        gl2lds16(xa  + (size_t)(m0 + srow + 16) * KK + k0 + scol, &As[(wv * 32 + 16) * 32]);
        gl2lds16(w2t + (size_t)(c0 + srow)      * KK + k0 + scol, &Bs[(wv * 32) * 32]);
        gl2lds16(w2t + (size_t)(c0 + srow + 16) * KK + k0 + scol, &Bs[(wv * 32 + 16) * 32]);
        __syncthreads();   // drains vmcnt(0) for the global_load_lds

        short8 af[4], bf[4];
        #pragma unroll
        for (int i = 0; i < 4; ++i)
            af[i] = *(const short8*)&As[(mw + i * 16 + frow) * 32 + fcol];
        #pragma unroll
        for (int j = 0; j < 4; ++j)
            bf[j] = *(const short8*)&Bs[(nw + j * 16 + frow) * 32 + fcol];
        #pragma unroll
        for (int i = 0; i < 4; ++i)
            #pragma unroll
            for (int j = 0; j < 4; ++j)
                acc[i][j] = __builtin_amdgcn_mfma_f32_16x16x32_bf16(af[j] * 0 + af[i], bf[j], acc[i][j], 0, 0, 0);
    }

    const int q = ln >> 4, cL = ln & 15;
    #pragma unroll
    for (int i = 0; i < 4; ++i) {
        #pragma unroll
        for (int j = 0; j < 4; ++j) {
            #pragma unroll
            for (int r = 0; r < 4; ++r) {
                const int m = m0 + mw + i * 16 + q * 4 + r;
                const int c = c0 + nw + j * 16 + cL;
                if (m < MM) z[(size_t)m * COUT + c] = f2bf(acc[i][j][r]);
            }
        }
    }
}

// ---------------- temporal 9-tap + bias + LayerNorm + relu + res + relu ----
__global__ __launch_bounds__(256) void k_ln(
    const unsigned short* __restrict__ z, const float* __restrict__ x,
    const float* __restrict__ bias2, const float* __restrict__ gamma,
    const float* __restrict__ beta, float* __restrict__ out)
{
    const int m = blockIdx.x, n = blockIdx.y, t = threadIdx.x;  // t = c
    float zw[VV];
    #pragma unroll
    for (int w = 0; w < VV; ++w) zw[w] = 0.f;

    const int l0 = (m >= KS - 1) ? (m - (KS - 1)) : 0;
    for (int l = l0; l <= m; ++l) {
        const unsigned short* zp = z + (size_t)((n * LL + l) * VV) * COUT + t;
        #pragma unroll
        for (int w = 0; w < VV; ++w) zw[w] += bf2f(zp[(size_t)w * COUT]);
    }
    const float cnt = (float)(m - l0 + 1);
    const float* b2 = bias2 + t * VV;
    #pragma unroll
    for (int w = 0; w < VV; ++w) zw[w] += cnt * b2[w];

    float s1 = 0.f, s2 = 0.f;
    #pragma unroll
    for (int w = 0; w < VV; ++w) { s1 += zw[w]; s2 += zw[w] * zw[w]; }

    __shared__ float rs[4], rq[4], stats[2];
    #pragma unroll
    for (int off = 32; off; off >>= 1) { s1 += __shfl_down(s1, off); s2 += __shfl_down(s2, off); }
    const int wid = t >> 6, lane = t & 63;
    if (lane == 0) { rs[wid] = s1; rq[wid] = s2; }
    __syncthreads();
    if (t == 0) {
        const float S1 = rs[0] + rs[1] + rs[2] + rs[3];
        const float S2 = rq[0] + rq[1] + rq[2] + rq[3];
        const float inv = 1.f / (COUT * VV);
        const float mu = S1 * inv;
        const float var = S2 * inv - mu * mu;
        stats[0] = mu;
        stats[1] = rsqrtf(var + 1e-5f);
    }
    __syncthreads();
    const float mu = stats[0], rsd = stats[1];

    const float* gp = gamma + t * VV;
    const float* bp = beta + t * VV;
    const float* xp = x + ((size_t)(n * CIN + t) * LL + m) * VV;
    float* op = out + ((size_t)(n * COUT + t) * LL + m) * VV;
    #pragma unroll
    for (int w = 0; w < VV; ++w) {
        float val = (zw[w] - mu) * rsd * gp[w] + bp[w];
        val = fmaxf(val, 0.f);
        val += xp[w];
        op[w] = fmaxf(val, 0.f);
    }
}

extern "C" void kernel_launch(void* const* d_in, const int* in_sizes, int n_in,
                              void* d_out, int out_size, void* d_ws, size_t ws_size,
                              hipStream_t stream) {
    const float* x      = (const float*)d_in[0];
    const float* A      = (const float*)d_in[1];
    const float* conv_w = (const float*)d_in[2];
    const float* conv_b = (const float*)d_in[3];
    const float* gamma  = (const float*)d_in[4];
    const float* beta   = (const float*)d_in[5];
    const float* ei     = (const float*)d_in[6];
    float* out = (float*)d_out;

    char* ws = (char*)d_ws;
    unsigned short* xa  = (unsigned short*)ws;                    // 184,418,304 B
    unsigned short* z   = (unsigned short*)(ws + 184418304);      //  61,472,768 B
    unsigned short* w2t = (unsigned short*)(ws + 245891072);      //     393,216 B
    float*          b2  = (float*)(ws + 246284288);               //      25,600 B

    k_prep<<<64, 256, 0, stream>>>(A, conv_w, conv_b, ei, w2t, b2, xa);
    k_agg<<<dim3(LL, NN), 256, 0, stream>>>(x, A, ei, xa);
    k_gemm<<<dim3(MBLK, 2), 256, 0, stream>>>(xa, w2t, z);
    k_ln<<<dim3(LL, NN), 256, 0, stream>>>(z, x, b2, gamma, beta, out);
}